// Round 5
// baseline (651.873 us; speedup 1.0000x reference)
//
#include <hip/hip_runtime.h>
#include <math.h>

// Problem constants
#define B_  16
#define L_  128
#define E_  34
#define A_  36
#define D_  300
#define H_  256
#define DP_ 304     // D padded to mult of 16
#define G4_ 1024    // 4*H
#define KC_ 512     // 2*H
#define NCAT_ 128   // padded 36(base)+36(trig)+34(evh)
#define WAS_ 1092   // Wa row stride = 4H + A-1 + E-1
#define WES_ 545    // We row stride = 2H + E-1

// Workspace layout (float offsets)
#define O_X      0u         // [2048][304] gathered embeddings (t*16+b rows)
#define O_WIHT_F 622592u    // [304][1024]
#define O_WIHT_B 933888u
#define O_HX     1245184u   // u64[2][128][64] tagged h exchange (parity dbuf)
#define O_BSUM_F 1769472u   // [1024] bih+bhh
#define O_BSUM_B 1770496u
#define O_ZPRE   1771520u   // [2][128][16][1024]  x@WihT + bias, in processing order
#define O_HIDDEN 5965824u   // [128][16][512]  hs-layout (t,b), fwd in [0:256), bwd in [256:512)
#define O_WCAT   7014400u   // [512][128]  cols: 0..35 Wa_hidden, 36..71 Wa_trig, 72..105 We_hidden
#define O_BVEC   7079936u   // [128]       ba | 0 | be
#define O_P      7080064u   // [2048][128] hidden @ Wcat + bvec   (rows m = t*16+b)
#define O_EVTAG  7342208u   // int [16][128]  self-tagged event preds ((i+1)<<8 | p)

#define HIX(k) ((k) + (((k) >> 5) << 2))   // +4 float pad per 32 to stagger banks

__device__ __forceinline__ float fsig(float x) {
    return __builtin_amdgcn_rcpf(1.0f + __expf(-x));
}
__device__ __forceinline__ float ftanh(float x) {
    float e = __expf(-2.0f * fabsf(x));          // (0,1] - no overflow
    float t = (1.0f - e) * __builtin_amdgcn_rcpf(1.0f + e);
    return copysignf(t, x);
}

// ---------------------------------------------------------------- prep (+gather)
__global__ void k_prep(const int* __restrict__ ids, const float* __restrict__ emb,
                       const float* __restrict__ Wih_f,
                       const float* __restrict__ bih_f, const float* __restrict__ bhh_f,
                       const float* __restrict__ Wih_b,
                       const float* __restrict__ bih_b, const float* __restrict__ bhh_b,
                       const float* __restrict__ We, const float* __restrict__ be,
                       const float* __restrict__ Wa, const float* __restrict__ ba,
                       float* __restrict__ ws) {
    const int N0 = 2048 * DP_;   // gathered embeddings
    const int N1 = 2 * 311296;   // WihT
    const int N3 = 2 * 1024;     // bsum
    const int N4 = 65536;        // Wcat
    const int N5 = 128;          // bvec
    const int total = N0 + N1 + N3 + N4 + N5;
    for (int idx = blockIdx.x * blockDim.x + threadIdx.x; idx < total;
         idx += gridDim.x * blockDim.x) {
        int i = idx;
        if (i < N0) {
            int m = i / DP_, d = i - m * DP_;   // m = t*16+b
            int t = m >> 4, b = m & 15;
            int id = ids[b * L_ + t];
            ws[O_X + i] = (d < D_) ? emb[(size_t)id * D_ + d] : 0.0f;
            continue;
        }
        i -= N0;
        if (i < N1) {
            int dir = i / 311296, rem = i % 311296;
            int k = rem >> 10, r = rem & 1023;
            const float* Wih = dir ? Wih_b : Wih_f;
            ws[(dir ? O_WIHT_B : O_WIHT_F) + rem] = (k < D_) ? Wih[r * D_ + k] : 0.0f;
            continue;
        }
        i -= N1;
        if (i < N3) {
            int dir = i / 1024, r = i % 1024;
            ws[(dir ? O_BSUM_B : O_BSUM_F) + r] =
                (dir ? bih_b[r] + bhh_b[r] : bih_f[r] + bhh_f[r]);
            continue;
        }
        i -= N3;
        if (i < N4) {
            int k = i >> 7, n = i & 127;
            float v = 0.0f;
            if (n < 36)               v = Wa[n * WAS_ + k];
            else if (n < 72)          v = Wa[(n - 36) * WAS_ + KC_ + k];
            else if (n < 106)         v = We[(n - 72) * WES_ + k];
            ws[O_WCAT + i] = v;
            continue;
        }
        i -= N4;
        {
            float v = 0.0f;
            if (i < 36)               v = ba[i];
            else if (i >= 72 && i < 106) v = be[i - 72];
            ws[O_BVEC + i] = v;
        }
    }
}

// ------------------------------------------------- GEMM1: z_pre = x @ WihT + bsum
__global__ __launch_bounds__(256) void k_gemm1(float* __restrict__ ws) {
    __shared__ float As[16][64];
    __shared__ float Bs[16][64];
    int dir = blockIdx.z;
    int m0 = blockIdx.y * 64;
    int n0 = blockIdx.x * 64;
    int tid = threadIdx.x;
    const float* xp = ws + O_X;
    const float* Bt = ws + (dir ? O_WIHT_B : O_WIHT_F);
    const float* bs = ws + (dir ? O_BSUM_B : O_BSUM_F);
    float acc[4][4] = {};
    int a_m = tid >> 2, a_k = (tid & 3) << 2;
    int b_k = tid >> 4, b_n = (tid & 15) << 2;
    int ty = tid >> 4, tx = tid & 15;
    int mrow = m0 + a_m;
    int t = mrow >> 4, bb = mrow & 15;
    int srow = dir ? (((L_ - 1 - t) << 4) | bb) : mrow;
    const float* arow = xp + (size_t)srow * DP_;
    for (int k0 = 0; k0 < DP_; k0 += 16) {
        float4 av = *(const float4*)(arow + k0 + a_k);
        float4 bv = *(const float4*)(Bt + (size_t)(k0 + b_k) * G4_ + n0 + b_n);
        As[a_k + 0][a_m] = av.x; As[a_k + 1][a_m] = av.y;
        As[a_k + 2][a_m] = av.z; As[a_k + 3][a_m] = av.w;
        *(float4*)&Bs[b_k][b_n] = bv;
        __syncthreads();
#pragma unroll
        for (int kk = 0; kk < 16; kk++) {
            float4 a4 = *(const float4*)&As[kk][ty * 4];
            float4 b4 = *(const float4*)&Bs[kk][tx * 4];
            acc[0][0] = fmaf(a4.x, b4.x, acc[0][0]); acc[0][1] = fmaf(a4.x, b4.y, acc[0][1]);
            acc[0][2] = fmaf(a4.x, b4.z, acc[0][2]); acc[0][3] = fmaf(a4.x, b4.w, acc[0][3]);
            acc[1][0] = fmaf(a4.y, b4.x, acc[1][0]); acc[1][1] = fmaf(a4.y, b4.y, acc[1][1]);
            acc[1][2] = fmaf(a4.y, b4.z, acc[1][2]); acc[1][3] = fmaf(a4.y, b4.w, acc[1][3]);
            acc[2][0] = fmaf(a4.z, b4.x, acc[2][0]); acc[2][1] = fmaf(a4.z, b4.y, acc[2][1]);
            acc[2][2] = fmaf(a4.z, b4.z, acc[2][2]); acc[2][3] = fmaf(a4.z, b4.w, acc[2][3]);
            acc[3][0] = fmaf(a4.w, b4.x, acc[3][0]); acc[3][1] = fmaf(a4.w, b4.y, acc[3][1]);
            acc[3][2] = fmaf(a4.w, b4.z, acc[3][2]); acc[3][3] = fmaf(a4.w, b4.w, acc[3][3]);
        }
        __syncthreads();
    }
    float4 bias = *(const float4*)(bs + n0 + tx * 4);
    float* zp = ws + O_ZPRE + ((size_t)dir * 2048 + m0) * G4_;
#pragma unroll
    for (int i = 0; i < 4; i++) {
        float4 o;
        o.x = acc[i][0] + bias.x; o.y = acc[i][1] + bias.y;
        o.z = acc[i][2] + bias.z; o.w = acc[i][3] + bias.w;
        *(float4*)(zp + (size_t)(ty * 4 + i) * G4_ + n0 + tx * 4) = o;
    }
}

// ------------------------------------------------- LSTM: 128 blocks
// phys = g*32 + (dir*16+b). Thread-group rg (8 lanes) owns h-row g*64+rg and holds
// all 4 gates' weight rows (gate*256 + hrow) -> after the 3-hop shuffle, lane kc==0
// holds z_i,z_f,z_g,z_o for its row: activation inline, no zbuf, no mid barrier.
// LDS h is parity double-buffered (read s&1, write (s+1)&1) -> WAR-safe with a
// single end-of-step barrier, emitted lgkm-only (no vmcnt store-ack drain).
// Cross-block h exchange: self-tagged u64 (tag<<32|bits), relaxed agent atomics.
__global__ __launch_bounds__(512, 2) void k_lstm(float* __restrict__ ws,
                                                 const float* __restrict__ Whh_f,
                                                 const float* __restrict__ Whh_b) {
    int phys = blockIdx.x;
    int g    = phys >> 5;
    int cb   = phys & 31;
    int b    = cb & 15;
    int dir  = cb >> 4;
    int tid  = threadIdx.x;
    int rg   = tid >> 3;             // 0..63 h-row within quarter
    int kc   = tid & 7;              // k chunk of 32

    const float* Whh  = dir ? Whh_b : Whh_f;
    const float* zpre = ws + O_ZPRE + (size_t)dir * 2048 * G4_;
    float* hid = ws + O_HIDDEN;
    unsigned long long* hx64 = (unsigned long long*)(ws + O_HX);

    __shared__ float h_sh[2][288];   // HIX(255)+1 = 284, padded

    int hrow = g * 64 + rg;          // 0..255
    float4 w[4][8];                  // [gate][kchunk]
#pragma unroll
    for (int i = 0; i < 4; i++) {
        const float* wr = Whh + (size_t)(i * 256 + hrow) * H_ + (kc << 5);
#pragma unroll
        for (int c = 0; c < 8; c++) w[i][c] = *(const float4*)(wr + (c << 2));
    }
    for (int k = tid; k < 2 * 288; k += 512) ((float*)h_sh)[k] = 0.0f;
    float c_state = 0.0f;
    float z0 = 0.f, z1 = 0.f, z2 = 0.f, z3 = 0.f;
    if (kc == 0) {
        const float* zr = zpre + (size_t)(0 * B_ + b) * G4_ + hrow;
        z0 = zr[0]; z1 = zr[256]; z2 = zr[512]; z3 = zr[768];
    }
    __syncthreads();

    for (int s = 0; s < L_; s++) {
        int cur = s & 1, nxt = cur ^ 1;
        float n0 = 0.f, n1 = 0.f, n2 = 0.f, n3 = 0.f;
        if (kc == 0 && s + 1 < L_) {
            const float* zr = zpre + (size_t)((s + 1) * B_ + b) * G4_ + hrow;
            n0 = zr[0]; n1 = zr[256]; n2 = zr[512]; n3 = zr[768];
        }
        float a0 = 0.f, a1 = 0.f, a2 = 0.f, a3 = 0.f;
        const float* hp = &h_sh[cur][kc * 36];
#pragma unroll
        for (int c = 0; c < 8; c++) {
            float4 hv = *(const float4*)(hp + (c << 2));
            a0 = fmaf(w[0][c].x, hv.x, a0); a0 = fmaf(w[0][c].y, hv.y, a0);
            a0 = fmaf(w[0][c].z, hv.z, a0); a0 = fmaf(w[0][c].w, hv.w, a0);
            a1 = fmaf(w[1][c].x, hv.x, a1); a1 = fmaf(w[1][c].y, hv.y, a1);
            a1 = fmaf(w[1][c].z, hv.z, a1); a1 = fmaf(w[1][c].w, hv.w, a1);
            a2 = fmaf(w[2][c].x, hv.x, a2); a2 = fmaf(w[2][c].y, hv.y, a2);
            a2 = fmaf(w[2][c].z, hv.z, a2); a2 = fmaf(w[2][c].w, hv.w, a2);
            a3 = fmaf(w[3][c].x, hv.x, a3); a3 = fmaf(w[3][c].y, hv.y, a3);
            a3 = fmaf(w[3][c].w, hv.w, a3); a3 = fmaf(w[3][c].z, hv.z, a3);
        }
#pragma unroll
        for (int m = 1; m < 8; m <<= 1) {
            a0 += __shfl_xor(a0, m); a1 += __shfl_xor(a1, m);
            a2 += __shfl_xor(a2, m); a3 += __shfl_xor(a3, m);
        }
        if (kc == 0) {
            float fi = fsig(a0 + z0);
            float ff = fsig(a1 + z1);
            float gg = ftanh(a2 + z2);
            float fo = fsig(a3 + z3);
            c_state = ff * c_state + fi * gg;
            float h = fo * ftanh(c_state);
            h_sh[nxt][HIX(hrow)] = h;
            int t_orig = dir ? (L_ - 1 - s) : s;
            hid[(size_t)(t_orig * B_ + b) * KC_ + dir * H_ + hrow] = h;
            if (s + 1 < L_) {
                unsigned long long pk =
                    ((unsigned long long)(unsigned)(s + 1) << 32) | (unsigned)__float_as_uint(h);
                __hip_atomic_store(&hx64[(nxt << 13) + (phys << 6) + rg], pk,
                                   __ATOMIC_RELAXED, __HIP_MEMORY_SCOPE_AGENT);
            }
        }
        asm volatile("" ::: "memory");   // publish region precedes poll region
        if (kc >= 1 && kc <= 3 && s + 1 < L_) {
            int sg = (g + kc) & 3;
            int sb = cb | (sg << 5);
            const unsigned long long* wp = &hx64[(nxt << 13) + (sb << 6) + rg];
            unsigned long long v;
            int cnt = 0;
            do {
                v = __hip_atomic_load(wp, __ATOMIC_RELAXED, __HIP_MEMORY_SCOPE_AGENT);
            } while ((int)(v >> 32) < s + 1 && ++cnt < (1 << 20));
            h_sh[nxt][HIX(sg * 64 + rg)] = __uint_as_float((unsigned)v);
        }
        z0 = n0; z1 = n1; z2 = n2; z3 = n3;
        asm volatile("s_waitcnt lgkmcnt(0)\n\ts_barrier" ::: "memory");
    }
}

// ------------------------------------------------- GEMM2: P = hidden @ Wcat + bvec
__global__ __launch_bounds__(256) void k_gemm2(float* __restrict__ ws) {
    __shared__ float As[16][64];
    __shared__ float Bs[16][64];
    int m0 = blockIdx.y * 64;
    int n0 = blockIdx.x * 64;
    int tid = threadIdx.x;
    const float* Ap = ws + O_HIDDEN;
    const float* Bp = ws + O_WCAT;
    const float* bv = ws + O_BVEC;
    float acc[4][4] = {};
    int a_m = tid >> 2, a_k = (tid & 3) << 2;
    int b_k = tid >> 4, b_n = (tid & 15) << 2;
    int ty = tid >> 4, tx = tid & 15;
    const float* arow = Ap + (size_t)(m0 + a_m) * KC_;
    for (int k0 = 0; k0 < KC_; k0 += 16) {
        float4 av = *(const float4*)(arow + k0 + a_k);
        float4 bvv = *(const float4*)(Bp + (size_t)(k0 + b_k) * NCAT_ + n0 + b_n);
        As[a_k + 0][a_m] = av.x; As[a_k + 1][a_m] = av.y;
        As[a_k + 2][a_m] = av.z; As[a_k + 3][a_m] = av.w;
        *(float4*)&Bs[b_k][b_n] = bvv;
        __syncthreads();
#pragma unroll
        for (int kk = 0; kk < 16; kk++) {
            float4 a4 = *(const float4*)&As[kk][ty * 4];
            float4 b4 = *(const float4*)&Bs[kk][tx * 4];
            acc[0][0] = fmaf(a4.x, b4.x, acc[0][0]); acc[0][1] = fmaf(a4.x, b4.y, acc[0][1]);
            acc[0][2] = fmaf(a4.x, b4.z, acc[0][2]); acc[0][3] = fmaf(a4.x, b4.w, acc[0][3]);
            acc[1][0] = fmaf(a4.y, b4.x, acc[1][0]); acc[1][1] = fmaf(a4.y, b4.y, acc[1][1]);
            acc[1][2] = fmaf(a4.y, b4.z, acc[1][2]); acc[1][3] = fmaf(a4.y, b4.w, acc[1][3]);
            acc[2][0] = fmaf(a4.z, b4.x, acc[2][0]); acc[2][1] = fmaf(a4.z, b4.y, acc[2][1]);
            acc[2][2] = fmaf(a4.z, b4.z, acc[2][2]); acc[2][3] = fmaf(a4.z, b4.w, acc[2][3]);
            acc[3][0] = fmaf(a4.w, b4.x, acc[3][0]); acc[3][1] = fmaf(a4.w, b4.y, acc[3][1]);
            acc[3][2] = fmaf(a4.w, b4.z, acc[3][2]); acc[3][3] = fmaf(a4.w, b4.w, acc[3][3]);
        }
        __syncthreads();
    }
    float4 bias = *(const float4*)(bv + n0 + tx * 4);
    float* Pp = ws + O_P + (size_t)m0 * NCAT_;
#pragma unroll
    for (int i = 0; i < 4; i++) {
        float4 o;
        o.x = acc[i][0] + bias.x; o.y = acc[i][1] + bias.y;
        o.z = acc[i][2] + bias.z; o.w = acc[i][3] + bias.w;
        *(float4*)(Pp + (size_t)(ty * 4 + i) * NCAT_ + n0 + tx * 4) = o;
    }
}

// ------------------------------------------------- fused decoder
// block 0: event chains (16 waves), publishes self-tagged preds evtag[b][i] = ((i+1)<<8)|p.
// blocks 1..128: 16 argument chains each; tags read via 64-wide window gather + shfl.
__global__ __launch_bounds__(1024) void k_dec(const float* __restrict__ We,
                                              const float* __restrict__ Wa,
                                              float* __restrict__ ws, float* __restrict__ out) {
    const float* P = ws + O_P;
    int* evtag = (int*)(ws + O_EVTAG);   // [16][128]
    int lane = threadIdx.x & 63;
    if (blockIdx.x == 0) {
        int b = threadIdx.x >> 6;
        float Cg = 0.0f;
        unsigned long long gmask = 0ull;
        float pv = (lane < E_) ? P[(size_t)(0 * B_ + b) * NCAT_ + 72 + lane] : 0.0f;
        for (int i = 0; i < L_; i++) {
            float pnext = 0.0f;
            if (i + 1 < L_ && lane < E_) pnext = P[(size_t)((i + 1) * B_ + b) * NCAT_ + 72 + lane];
            float v = (lane < E_) ? (pv + Cg) : -INFINITY;
            float mv = v;
            int mi = (lane < E_) ? lane : 0x7fffffff;
#pragma unroll
            for (int off = 32; off; off >>= 1) {
                float ov = __shfl_down(mv, off);
                int oi = __shfl_down(mi, off);
                if (ov > mv || (ov == mv && oi < mi)) { mv = ov; mi = oi; }
            }
            int p = __shfl(mi, 0);
            if (lane < E_) out[(size_t)(b * L_ + i) * E_ + lane] = v;
            if (lane == 0)
                __hip_atomic_store(&evtag[b * L_ + i], ((i + 1) << 8) | p,
                                   __ATOMIC_RELAXED, __HIP_MEMORY_SCOPE_AGENT);
            if (p > 0) {
                unsigned long long bit = 1ull << (p - 1);
                if (!(gmask & bit)) {
                    gmask |= bit;
                    if (lane < E_) Cg += We[lane * WES_ + 2 * H_ + (p - 1)];
                }
            }
            pv = pnext;
        }
    } else {
        int w = ((blockIdx.x - 1) << 4) + (threadIdx.x >> 6);  // 0..2047
        int b = w >> 7, j = w & 127;
        float* outa = out + (size_t)B_ * L_ * E_;
        float C = 0.0f;
        if (lane < A_) C = P[(size_t)(j * B_ + b) * NCAT_ + lane];
        unsigned long long ga = 0ull, gta = 0ull;
        float tv = (lane < A_) ? P[(size_t)(0 * B_ + b) * NCAT_ + 36 + lane] : 0.0f;
        int myv = (int)0x80000000;   // cached tag word for window slot `lane`
        for (int i = 0; i < L_; i++) {
            float tnext = 0.0f;
            if (i + 1 < L_ && lane < A_) tnext = P[(size_t)((i + 1) * B_ + b) * NCAT_ + 36 + lane];
            int w0 = i & ~63;
            if ((i & 63) == 0)
                myv = __hip_atomic_load(&evtag[b * L_ + w0 + lane],
                                        __ATOMIC_RELAXED, __HIP_MEMORY_SCOPE_AGENT);
            int tv_tag = __shfl(myv, i & 63);
            int cnt = 0;
            while ((tv_tag >> 8) < i + 1 && cnt < (1 << 20)) {
                myv = __hip_atomic_load(&evtag[b * L_ + w0 + lane],
                                        __ATOMIC_RELAXED, __HIP_MEMORY_SCOPE_AGENT);
                tv_tag = __shfl(myv, i & 63);
                cnt++;
            }
            int ev = tv_tag & 0xff;
            float v = (lane < A_) ? (C + tv) : -INFINITY;
            float mv = v;
            int mi = (lane < A_) ? lane : 0x7fffffff;
#pragma unroll
            for (int off = 32; off; off >>= 1) {
                float ov = __shfl_down(mv, off);
                int oi = __shfl_down(mi, off);
                if (ov > mv || (ov == mv && oi < mi)) { mv = ov; mi = oi; }
            }
            int p = __shfl(mi, 0);
            if (lane < A_) outa[(size_t)((b * L_ + i) * L_ + j) * A_ + lane] = v;
            if (ev > 0 && p > 0) {
                unsigned long long bq = 1ull << (ev - 1);
                if (!(gta & bq)) {
                    gta |= bq;
                    if (lane < A_) C += Wa[lane * WAS_ + 4 * H_ + A_ - 1 + (ev - 1)];
                }
                unsigned long long br = 1ull << (p - 1);
                if (!(ga & br)) {
                    ga |= br;
                    if (lane < A_) C += Wa[lane * WAS_ + 4 * H_ + (p - 1)];
                }
            }
            tv = tnext;
        }
    }
}

// ----------------------------------------------------------------
extern "C" void kernel_launch(void* const* d_in, const int* in_sizes, int n_in,
                              void* d_out, int out_size, void* d_ws, size_t ws_size,
                              hipStream_t stream) {
    (void)in_sizes; (void)n_in; (void)out_size; (void)ws_size;
    const int*   ids   = (const int*)d_in[0];
    const float* emb   = (const float*)d_in[1];
    const float* Wih_f = (const float*)d_in[2];
    const float* Whh_f = (const float*)d_in[3];
    const float* bih_f = (const float*)d_in[4];
    const float* bhh_f = (const float*)d_in[5];
    const float* Wih_b = (const float*)d_in[6];
    const float* Whh_b = (const float*)d_in[7];
    const float* bih_b = (const float*)d_in[8];
    const float* bhh_b = (const float*)d_in[9];
    const float* We    = (const float*)d_in[10];
    const float* be    = (const float*)d_in[11];
    const float* Wa    = (const float*)d_in[12];
    const float* ba    = (const float*)d_in[13];
    float* out = (float*)d_out;
    float* ws  = (float*)d_ws;

    hipLaunchKernelGGL(k_prep, dim3(2048), dim3(256), 0, stream,
                       ids, emb, Wih_f, bih_f, bhh_f, Wih_b, bih_b, bhh_b,
                       We, be, Wa, ba, ws);
    hipLaunchKernelGGL(k_gemm1, dim3(16, 32, 2), dim3(256), 0, stream, ws);
    hipLaunchKernelGGL(k_lstm, dim3(128), dim3(512), 0, stream, ws, Whh_f, Whh_b);
    hipLaunchKernelGGL(k_gemm2, dim3(2, 32, 1), dim3(256), 0, stream, ws);
    hipLaunchKernelGGL(k_dec, dim3(129), dim3(1024), 0, stream, We, Wa, ws, out);
}

// Round 6
// 527.389 us; speedup vs baseline: 1.2360x; 1.2360x over previous
//
#include <hip/hip_runtime.h>
#include <math.h>

// Problem constants
#define B_  16
#define L_  128
#define E_  34
#define A_  36
#define D_  300
#define H_  256
#define DP_ 304     // D padded to mult of 16
#define G4_ 1024    // 4*H
#define KC_ 512     // 2*H
#define NCAT_ 128   // padded 36(base)+36(trig)+34(evh)
#define WAS_ 1092   // Wa row stride = 4H + A-1 + E-1
#define WES_ 545    // We row stride = 2H + E-1

// Workspace layout (float offsets)
#define O_X      0u         // [2048][304] gathered embeddings (t*16+b rows)
#define O_WIHT_F 622592u    // [304][1024]
#define O_WIHT_B 933888u
#define O_HX     1245184u   // u64[2][128][64] tagged h exchange (parity dbuf)
#define O_BSUM_F 1769472u   // [1024] bih+bhh
#define O_BSUM_B 1770496u
#define O_ZPRE   1771520u   // [2][128][16][1024]  x@WihT + bias, in processing order
#define O_HIDDEN 5965824u   // [128][16][512]  hs-layout (t,b), fwd in [0:256), bwd in [256:512)
#define O_WCAT   7014400u   // [512][128]  cols: 0..35 Wa_hidden, 36..71 Wa_trig, 72..105 We_hidden
#define O_BVEC   7079936u   // [128]       ba | 0 | be
#define O_P      7080064u   // [2048][128] hidden @ Wcat + bvec   (rows m = t*16+b)
#define O_EVTAG  7342208u   // int [16][128]  self-tagged event preds ((i+1)<<8 | p)

#define HIX(k) ((k) + (((k) >> 5) << 2))   // +4 float pad per 32 to stagger banks

// lgkm-only barrier: skips the vmcnt(0) store-ack/prefetch drain __syncthreads emits.
// Safe when the barrier only orders LDS traffic (global deps handled by data deps).
#define BARRIER_LGKM() asm volatile("s_waitcnt lgkmcnt(0)\n\ts_barrier" ::: "memory")

__device__ __forceinline__ float fsig(float x) {
    return __builtin_amdgcn_rcpf(1.0f + __expf(-x));
}
__device__ __forceinline__ float ftanh(float x) {
    float e = __expf(-2.0f * fabsf(x));          // (0,1] - no overflow
    float t = (1.0f - e) * __builtin_amdgcn_rcpf(1.0f + e);
    return copysignf(t, x);
}

// ---------------------------------------------------------------- prep (+gather)
__global__ void k_prep(const int* __restrict__ ids, const float* __restrict__ emb,
                       const float* __restrict__ Wih_f,
                       const float* __restrict__ bih_f, const float* __restrict__ bhh_f,
                       const float* __restrict__ Wih_b,
                       const float* __restrict__ bih_b, const float* __restrict__ bhh_b,
                       const float* __restrict__ We, const float* __restrict__ be,
                       const float* __restrict__ Wa, const float* __restrict__ ba,
                       float* __restrict__ ws) {
    const int N0 = 2048 * DP_;   // gathered embeddings
    const int N1 = 2 * 311296;   // WihT
    const int N3 = 2 * 1024;     // bsum
    const int N4 = 65536;        // Wcat
    const int N5 = 128;          // bvec
    const int total = N0 + N1 + N3 + N4 + N5;
    for (int idx = blockIdx.x * blockDim.x + threadIdx.x; idx < total;
         idx += gridDim.x * blockDim.x) {
        int i = idx;
        if (i < N0) {
            int m = i / DP_, d = i - m * DP_;   // m = t*16+b
            int t = m >> 4, b = m & 15;
            int id = ids[b * L_ + t];
            ws[O_X + i] = (d < D_) ? emb[(size_t)id * D_ + d] : 0.0f;
            continue;
        }
        i -= N0;
        if (i < N1) {
            int dir = i / 311296, rem = i % 311296;
            int k = rem >> 10, r = rem & 1023;
            const float* Wih = dir ? Wih_b : Wih_f;
            ws[(dir ? O_WIHT_B : O_WIHT_F) + rem] = (k < D_) ? Wih[r * D_ + k] : 0.0f;
            continue;
        }
        i -= N1;
        if (i < N3) {
            int dir = i / 1024, r = i % 1024;
            ws[(dir ? O_BSUM_B : O_BSUM_F) + r] =
                (dir ? bih_b[r] + bhh_b[r] : bih_f[r] + bhh_f[r]);
            continue;
        }
        i -= N3;
        if (i < N4) {
            int k = i >> 7, n = i & 127;
            float v = 0.0f;
            if (n < 36)               v = Wa[n * WAS_ + k];
            else if (n < 72)          v = Wa[(n - 36) * WAS_ + KC_ + k];
            else if (n < 106)         v = We[(n - 72) * WES_ + k];
            ws[O_WCAT + i] = v;
            continue;
        }
        i -= N4;
        {
            float v = 0.0f;
            if (i < 36)               v = ba[i];
            else if (i >= 72 && i < 106) v = be[i - 72];
            ws[O_BVEC + i] = v;
        }
    }
}

// ------------------------------------------------- GEMM1: z_pre = x @ WihT + bsum
__global__ __launch_bounds__(256) void k_gemm1(float* __restrict__ ws) {
    __shared__ float As[16][64];
    __shared__ float Bs[16][64];
    int dir = blockIdx.z;
    int m0 = blockIdx.y * 64;
    int n0 = blockIdx.x * 64;
    int tid = threadIdx.x;
    const float* xp = ws + O_X;
    const float* Bt = ws + (dir ? O_WIHT_B : O_WIHT_F);
    const float* bs = ws + (dir ? O_BSUM_B : O_BSUM_F);
    float acc[4][4] = {};
    int a_m = tid >> 2, a_k = (tid & 3) << 2;
    int b_k = tid >> 4, b_n = (tid & 15) << 2;
    int ty = tid >> 4, tx = tid & 15;
    int mrow = m0 + a_m;
    int t = mrow >> 4, bb = mrow & 15;
    int srow = dir ? (((L_ - 1 - t) << 4) | bb) : mrow;
    const float* arow = xp + (size_t)srow * DP_;
    for (int k0 = 0; k0 < DP_; k0 += 16) {
        float4 av = *(const float4*)(arow + k0 + a_k);
        float4 bv = *(const float4*)(Bt + (size_t)(k0 + b_k) * G4_ + n0 + b_n);
        As[a_k + 0][a_m] = av.x; As[a_k + 1][a_m] = av.y;
        As[a_k + 2][a_m] = av.z; As[a_k + 3][a_m] = av.w;
        *(float4*)&Bs[b_k][b_n] = bv;
        __syncthreads();
#pragma unroll
        for (int kk = 0; kk < 16; kk++) {
            float4 a4 = *(const float4*)&As[kk][ty * 4];
            float4 b4 = *(const float4*)&Bs[kk][tx * 4];
            acc[0][0] = fmaf(a4.x, b4.x, acc[0][0]); acc[0][1] = fmaf(a4.x, b4.y, acc[0][1]);
            acc[0][2] = fmaf(a4.x, b4.z, acc[0][2]); acc[0][3] = fmaf(a4.x, b4.w, acc[0][3]);
            acc[1][0] = fmaf(a4.y, b4.x, acc[1][0]); acc[1][1] = fmaf(a4.y, b4.y, acc[1][1]);
            acc[1][2] = fmaf(a4.y, b4.z, acc[1][2]); acc[1][3] = fmaf(a4.y, b4.w, acc[1][3]);
            acc[2][0] = fmaf(a4.z, b4.x, acc[2][0]); acc[2][1] = fmaf(a4.z, b4.y, acc[2][1]);
            acc[2][2] = fmaf(a4.z, b4.z, acc[2][2]); acc[2][3] = fmaf(a4.z, b4.w, acc[2][3]);
            acc[3][0] = fmaf(a4.w, b4.x, acc[3][0]); acc[3][1] = fmaf(a4.w, b4.y, acc[3][1]);
            acc[3][2] = fmaf(a4.w, b4.z, acc[3][2]); acc[3][3] = fmaf(a4.w, b4.w, acc[3][3]);
        }
        __syncthreads();
    }
    float4 bias = *(const float4*)(bs + n0 + tx * 4);
    float* zp = ws + O_ZPRE + ((size_t)dir * 2048 + m0) * G4_;
#pragma unroll
    for (int i = 0; i < 4; i++) {
        float4 o;
        o.x = acc[i][0] + bias.x; o.y = acc[i][1] + bias.y;
        o.z = acc[i][2] + bias.z; o.w = acc[i][3] + bias.w;
        *(float4*)(zp + (size_t)(ty * 4 + i) * G4_ + n0 + tx * 4) = o;
    }
}

// ------------------------------------------------- LSTM: 128 blocks (round-4 protocol)
// phys = g*32 + (dir*16+b). Thread rg owns 4 consecutive gate rows of one gate;
// kc==0 writes z to zbuf; wave0 does activation + ONE coalesced 512B publish;
// waves 1-3 do coalesced polls of self-tagged u64s (relaxed agent atomics).
// Both barriers lgkm-only: no vmcnt store-ack / prefetch drain on the critical path.
// Single h_sh buffer is WAR-safe: reads (FMA) precede barrier1, writes follow it.
__global__ __launch_bounds__(512, 2) void k_lstm(float* __restrict__ ws,
                                                 const float* __restrict__ Whh_f,
                                                 const float* __restrict__ Whh_b) {
    int phys = blockIdx.x;
    int g    = phys >> 5;
    int cb   = phys & 31;
    int b    = cb & 15;
    int dir  = cb >> 4;
    int tid  = threadIdx.x;
    int rg   = tid >> 3;             // 0..63 -> 4 local gate rows each
    int kc   = tid & 7;              // 0..7  -> k chunk of 32

    const float* Whh  = dir ? Whh_b : Whh_f;
    const float* zpre = ws + O_ZPRE + (size_t)dir * 2048 * G4_;
    float* hid = ws + O_HIDDEN;
    unsigned long long* hx64 = (unsigned long long*)(ws + O_HX);

    __shared__ float h_sh[HIX(255) + 1 + 4];
    __shared__ float zbuf[256];

    int lr0  = rg << 2;
    int ggr0 = (lr0 >> 6) * 256 + g * 64 + (lr0 & 63);
    float4 w[4][8];
#pragma unroll
    for (int i = 0; i < 4; i++) {
        const float* wr = Whh + (size_t)(ggr0 + i) * H_ + (kc << 5);
#pragma unroll
        for (int c = 0; c < 8; c++) w[i][c] = *(const float4*)(wr + (c << 2));
    }
    for (int k = tid; k < HIX(255) + 1 + 4; k += 512) h_sh[k] = 0.0f;
    float c_state = 0.0f;
    float4 zv = make_float4(0.f, 0.f, 0.f, 0.f);
    if (kc == 0) zv = *(const float4*)(zpre + (size_t)(0 * B_ + b) * G4_ + ggr0);
    __syncthreads();

    for (int s = 0; s < L_; s++) {
        float4 zn = make_float4(0.f, 0.f, 0.f, 0.f);
        if (kc == 0 && s + 1 < L_)
            zn = *(const float4*)(zpre + (size_t)((s + 1) * B_ + b) * G4_ + ggr0);
        float a0 = 0.f, a1 = 0.f, a2 = 0.f, a3 = 0.f;
        const float* hp = &h_sh[kc * 36];
#pragma unroll
        for (int c = 0; c < 8; c++) {
            float4 hv = *(const float4*)(hp + (c << 2));
            a0 = fmaf(w[0][c].x, hv.x, a0); a0 = fmaf(w[0][c].y, hv.y, a0);
            a0 = fmaf(w[0][c].z, hv.z, a0); a0 = fmaf(w[0][c].w, hv.w, a0);
            a1 = fmaf(w[1][c].x, hv.x, a1); a1 = fmaf(w[1][c].y, hv.y, a1);
            a1 = fmaf(w[1][c].z, hv.z, a1); a1 = fmaf(w[1][c].w, hv.w, a1);
            a2 = fmaf(w[2][c].x, hv.x, a2); a2 = fmaf(w[2][c].y, hv.y, a2);
            a2 = fmaf(w[2][c].z, hv.z, a2); a2 = fmaf(w[2][c].w, hv.w, a2);
            a3 = fmaf(w[3][c].x, hv.x, a3); a3 = fmaf(w[3][c].y, hv.y, a3);
            a3 = fmaf(w[3][c].z, hv.z, a3); a3 = fmaf(w[3][c].w, hv.w, a3);
        }
#pragma unroll
        for (int m = 1; m < 8; m <<= 1) {
            a0 += __shfl_xor(a0, m); a1 += __shfl_xor(a1, m);
            a2 += __shfl_xor(a2, m); a3 += __shfl_xor(a3, m);
        }
        if (kc == 0) {
            float4 z4;
            z4.x = a0 + zv.x; z4.y = a1 + zv.y; z4.z = a2 + zv.z; z4.w = a3 + zv.w;
            *(float4*)&zbuf[lr0] = z4;
        }
        zv = zn;
        BARRIER_LGKM();
        int par = (s + 1) & 1;
        if (tid < 64) {
            float fi = fsig(zbuf[tid]);
            float ff = fsig(zbuf[tid + 64]);
            float gg = ftanh(zbuf[tid + 128]);
            float fo = fsig(zbuf[tid + 192]);
            c_state = ff * c_state + fi * gg;
            float h = fo * ftanh(c_state);
            int hr = g * 64 + tid;
            h_sh[HIX(hr)] = h;
            int t_orig = dir ? (L_ - 1 - s) : s;
            hid[(size_t)(t_orig * B_ + b) * KC_ + dir * H_ + hr] = h;
            if (s + 1 < L_) {
                unsigned long long pk =
                    ((unsigned long long)(unsigned)(s + 1) << 32) | (unsigned)__float_as_uint(h);
                __hip_atomic_store(&hx64[(par << 13) + (phys << 6) + tid], pk,
                                   __ATOMIC_RELAXED, __HIP_MEMORY_SCOPE_AGENT);
            }
        }
        if (tid >= 64 && tid < 256 && s + 1 < L_) {
            int which = tid >> 6;                 // 1..3
            int sg = (g + which) & 3;
            int sb = cb | (sg << 5);              // sibling physical block id
            int u  = tid & 63;
            const unsigned long long* wp = &hx64[(par << 13) + (sb << 6) + u];
            unsigned long long v;
            int cnt = 0;
            do {
                v = __hip_atomic_load(wp, __ATOMIC_RELAXED, __HIP_MEMORY_SCOPE_AGENT);
            } while ((int)(v >> 32) < s + 1 && ++cnt < (1 << 20));
            h_sh[HIX(sg * 64 + u)] = __uint_as_float((unsigned)v);
        }
        BARRIER_LGKM();
    }
}

// ------------------------------------------------- GEMM2: P = hidden @ Wcat + bvec
__global__ __launch_bounds__(256) void k_gemm2(float* __restrict__ ws) {
    __shared__ float As[16][64];
    __shared__ float Bs[16][64];
    int m0 = blockIdx.y * 64;
    int n0 = blockIdx.x * 64;
    int tid = threadIdx.x;
    const float* Ap = ws + O_HIDDEN;
    const float* Bp = ws + O_WCAT;
    const float* bv = ws + O_BVEC;
    float acc[4][4] = {};
    int a_m = tid >> 2, a_k = (tid & 3) << 2;
    int b_k = tid >> 4, b_n = (tid & 15) << 2;
    int ty = tid >> 4, tx = tid & 15;
    const float* arow = Ap + (size_t)(m0 + a_m) * KC_;
    for (int k0 = 0; k0 < KC_; k0 += 16) {
        float4 av = *(const float4*)(arow + k0 + a_k);
        float4 bvv = *(const float4*)(Bp + (size_t)(k0 + b_k) * NCAT_ + n0 + b_n);
        As[a_k + 0][a_m] = av.x; As[a_k + 1][a_m] = av.y;
        As[a_k + 2][a_m] = av.z; As[a_k + 3][a_m] = av.w;
        *(float4*)&Bs[b_k][b_n] = bvv;
        __syncthreads();
#pragma unroll
        for (int kk = 0; kk < 16; kk++) {
            float4 a4 = *(const float4*)&As[kk][ty * 4];
            float4 b4 = *(const float4*)&Bs[kk][tx * 4];
            acc[0][0] = fmaf(a4.x, b4.x, acc[0][0]); acc[0][1] = fmaf(a4.x, b4.y, acc[0][1]);
            acc[0][2] = fmaf(a4.x, b4.z, acc[0][2]); acc[0][3] = fmaf(a4.x, b4.w, acc[0][3]);
            acc[1][0] = fmaf(a4.y, b4.x, acc[1][0]); acc[1][1] = fmaf(a4.y, b4.y, acc[1][1]);
            acc[1][2] = fmaf(a4.y, b4.z, acc[1][2]); acc[1][3] = fmaf(a4.y, b4.w, acc[1][3]);
            acc[2][0] = fmaf(a4.z, b4.x, acc[2][0]); acc[2][1] = fmaf(a4.z, b4.y, acc[2][1]);
            acc[2][2] = fmaf(a4.z, b4.z, acc[2][2]); acc[2][3] = fmaf(a4.z, b4.w, acc[2][3]);
            acc[3][0] = fmaf(a4.w, b4.x, acc[3][0]); acc[3][1] = fmaf(a4.w, b4.y, acc[3][1]);
            acc[3][2] = fmaf(a4.w, b4.z, acc[3][2]); acc[3][3] = fmaf(a4.w, b4.w, acc[3][3]);
        }
        __syncthreads();
    }
    float4 bias = *(const float4*)(bv + n0 + tx * 4);
    float* Pp = ws + O_P + (size_t)m0 * NCAT_;
#pragma unroll
    for (int i = 0; i < 4; i++) {
        float4 o;
        o.x = acc[i][0] + bias.x; o.y = acc[i][1] + bias.y;
        o.z = acc[i][2] + bias.z; o.w = acc[i][3] + bias.w;
        *(float4*)(Pp + (size_t)(ty * 4 + i) * NCAT_ + n0 + tx * 4) = o;
    }
}

// ------------------------------------------------- fused decoder
// block 0: event chains (16 waves), publishes self-tagged preds evtag[b][i] = ((i+1)<<8)|p.
// blocks 1..128: 16 argument chains each; tag polls use s_sleep backoff on miss
// (2048 waves otherwise hammer the same 128 IC lines and throttle the ev chain).
// Both chains prefetch their P rows 2 steps ahead (IC RTT > per-step compute).
__global__ __launch_bounds__(1024) void k_dec(const float* __restrict__ We,
                                              const float* __restrict__ Wa,
                                              float* __restrict__ ws, float* __restrict__ out) {
    const float* P = ws + O_P;
    int* evtag = (int*)(ws + O_EVTAG);   // [16][128]
    int lane = threadIdx.x & 63;
    if (blockIdx.x == 0) {
        int b = threadIdx.x >> 6;
        float Cg = 0.0f;
        unsigned long long gmask = 0ull;
        float pv = (lane < E_) ? P[(size_t)(0 * B_ + b) * NCAT_ + 72 + lane] : 0.0f;
        float p1 = (lane < E_) ? P[(size_t)(1 * B_ + b) * NCAT_ + 72 + lane] : 0.0f;
        for (int i = 0; i < L_; i++) {
            float p2 = 0.0f;
            if (i + 2 < L_ && lane < E_) p2 = P[(size_t)((i + 2) * B_ + b) * NCAT_ + 72 + lane];
            float v = (lane < E_) ? (pv + Cg) : -INFINITY;
            float mv = v;
            int mi = (lane < E_) ? lane : 0x7fffffff;
#pragma unroll
            for (int off = 32; off; off >>= 1) {
                float ov = __shfl_down(mv, off);
                int oi = __shfl_down(mi, off);
                if (ov > mv || (ov == mv && oi < mi)) { mv = ov; mi = oi; }
            }
            int p = __shfl(mi, 0);
            if (lane == 0)
                __hip_atomic_store(&evtag[b * L_ + i], ((i + 1) << 8) | p,
                                   __ATOMIC_RELAXED, __HIP_MEMORY_SCOPE_AGENT);
            if (lane < E_) out[(size_t)(b * L_ + i) * E_ + lane] = v;
            if (p > 0) {
                unsigned long long bit = 1ull << (p - 1);
                if (!(gmask & bit)) {
                    gmask |= bit;
                    if (lane < E_) Cg += We[lane * WES_ + 2 * H_ + (p - 1)];
                }
            }
            pv = p1; p1 = p2;
        }
    } else {
        int w = ((blockIdx.x - 1) << 4) + (threadIdx.x >> 6);  // 0..2047
        int b = w >> 7, j = w & 127;
        float* outa = out + (size_t)B_ * L_ * E_;
        float C = 0.0f;
        if (lane < A_) C = P[(size_t)(j * B_ + b) * NCAT_ + lane];
        unsigned long long ga = 0ull, gta = 0ull;
        float tv = (lane < A_) ? P[(size_t)(0 * B_ + b) * NCAT_ + 36 + lane] : 0.0f;
        float t1 = (lane < A_) ? P[(size_t)(1 * B_ + b) * NCAT_ + 36 + lane] : 0.0f;
        int myv = (int)0x80000000;   // cached tag word for window slot `lane`
        for (int i = 0; i < L_; i++) {
            float t2 = 0.0f;
            if (i + 2 < L_ && lane < A_) t2 = P[(size_t)((i + 2) * B_ + b) * NCAT_ + 36 + lane];
            int w0 = i & ~63;
            if ((i & 63) == 0)
                myv = __hip_atomic_load(&evtag[b * L_ + w0 + lane],
                                        __ATOMIC_RELAXED, __HIP_MEMORY_SCOPE_AGENT);
            int tv_tag = __shfl(myv, i & 63);
            if ((tv_tag >> 8) < i + 1) {   // wave-uniform miss: backoff poll
                int cnt = 0;
                do {
                    __builtin_amdgcn_s_sleep(1);
                    myv = __hip_atomic_load(&evtag[b * L_ + w0 + lane],
                                            __ATOMIC_RELAXED, __HIP_MEMORY_SCOPE_AGENT);
                    tv_tag = __shfl(myv, i & 63);
                } while ((tv_tag >> 8) < i + 1 && ++cnt < (1 << 18));
            }
            int ev = tv_tag & 0xff;
            float v = (lane < A_) ? (C + tv) : -INFINITY;
            float mv = v;
            int mi = (lane < A_) ? lane : 0x7fffffff;
#pragma unroll
            for (int off = 32; off; off >>= 1) {
                float ov = __shfl_down(mv, off);
                int oi = __shfl_down(mi, off);
                if (ov > mv || (ov == mv && oi < mi)) { mv = ov; mi = oi; }
            }
            int p = __shfl(mi, 0);
            if (lane < A_) outa[(size_t)((b * L_ + i) * L_ + j) * A_ + lane] = v;
            if (ev > 0 && p > 0) {
                unsigned long long bq = 1ull << (ev - 1);
                if (!(gta & bq)) {
                    gta |= bq;
                    if (lane < A_) C += Wa[lane * WAS_ + 4 * H_ + A_ - 1 + (ev - 1)];
                }
                unsigned long long br = 1ull << (p - 1);
                if (!(ga & br)) {
                    ga |= br;
                    if (lane < A_) C += Wa[lane * WAS_ + 4 * H_ + (p - 1)];
                }
            }
            tv = t1; t1 = t2;
        }
    }
}

// ----------------------------------------------------------------
extern "C" void kernel_launch(void* const* d_in, const int* in_sizes, int n_in,
                              void* d_out, int out_size, void* d_ws, size_t ws_size,
                              hipStream_t stream) {
    (void)in_sizes; (void)n_in; (void)out_size; (void)ws_size;
    const int*   ids   = (const int*)d_in[0];
    const float* emb   = (const float*)d_in[1];
    const float* Wih_f = (const float*)d_in[2];
    const float* Whh_f = (const float*)d_in[3];
    const float* bih_f = (const float*)d_in[4];
    const float* bhh_f = (const float*)d_in[5];
    const float* Wih_b = (const float*)d_in[6];
    const float* Whh_b = (const float*)d_in[7];
    const float* bih_b = (const float*)d_in[8];
    const float* bhh_b = (const float*)d_in[9];
    const float* We    = (const float*)d_in[10];
    const float* be    = (const float*)d_in[11];
    const float* Wa    = (const float*)d_in[12];
    const float* ba    = (const float*)d_in[13];
    float* out = (float*)d_out;
    float* ws  = (float*)d_ws;

    hipLaunchKernelGGL(k_prep, dim3(2048), dim3(256), 0, stream,
                       ids, emb, Wih_f, bih_f, bhh_f, Wih_b, bih_b, bhh_b,
                       We, be, Wa, ba, ws);
    hipLaunchKernelGGL(k_gemm1, dim3(16, 32, 2), dim3(256), 0, stream, ws);
    hipLaunchKernelGGL(k_lstm, dim3(128), dim3(512), 0, stream, ws, Whh_f, Whh_b);
    hipLaunchKernelGGL(k_gemm2, dim3(2, 32, 1), dim3(256), 0, stream, ws);
    hipLaunchKernelGGL(k_dec, dim3(129), dim3(1024), 0, stream, We, Wa, ws, out);
}